// Round 2
// baseline (657.136 us; speedup 1.0000x reference)
//
#include <hip/hip_runtime.h>
#include <hip/hip_bf16.h>
#include <math.h>

#define N_NODES 20000
#define N_EDGES 320000
#define IN_DIM 128
#define HID 256
#define HEADS 8
#define DH 32
#define LAYERS 3
#define NUM_GRAPHS 64
#define OUT_DIM 10
#define SLOPE 0.2f

// ---------------- utility kernels ----------------
__global__ void zero_kernel(float* __restrict__ p, int n) {
    int i = blockIdx.x * blockDim.x + threadIdx.x;
    if (i < n) p[i] = 0.f;
}

// ---------------- CSR build (group edges by dst) ----------------
__global__ void count_kernel(const int* __restrict__ dst, int* __restrict__ cnt) {
    int e = blockIdx.x * blockDim.x + threadIdx.x;
    if (e < N_EDGES) atomicAdd(&cnt[dst[e]], 1);
}

__global__ __launch_bounds__(256) void scan_kernel(const int* __restrict__ cnt,
                                                   int* __restrict__ offs,
                                                   int* __restrict__ cursor) {
    __shared__ int part[256];
    int t = threadIdx.x;
    const int chunk = (N_NODES + 255) / 256;  // 79
    int beg = t * chunk;
    int end = beg + chunk; if (end > N_NODES) end = N_NODES;
    int s = 0;
    for (int i = beg; i < end; ++i) s += cnt[i];
    part[t] = s;
    __syncthreads();
    if (t == 0) {
        int run = 0;
        for (int i = 0; i < 256; ++i) { int v = part[i]; part[i] = run; run += v; }
        offs[N_NODES] = run;
    }
    __syncthreads();
    int run = part[t];
    for (int i = beg; i < end; ++i) {
        offs[i] = run; cursor[i] = run; run += cnt[i];
    }
}

__global__ void fill_kernel(const int* __restrict__ src, const int* __restrict__ dst,
                            int* __restrict__ cursor, int* __restrict__ csr_src) {
    int e = blockIdx.x * blockDim.x + threadIdx.x;
    if (e < N_EDGES) {
        int p = atomicAdd(&cursor[dst[e]], 1);
        csr_src[p] = src[e];
    }
}

// ---------------- GEMM: C[M,N] = A[M,K] @ B[K,N] + bias, all fp32 ----------------
// 64x64 tile / 256 threads / 4x4 micro-tile.
__global__ __launch_bounds__(256) void gemm_kernel(
    const float* __restrict__ A, const float* __restrict__ B,
    const float* __restrict__ bias, float* __restrict__ C,
    int M, int K, int N) {
    __shared__ float As[64][17];   // [m][k], pad to break bank stride
    __shared__ float Bs[16][64];   // [k][n]

    int t = threadIdx.x;
    int tx = t % 16, ty = t / 16;
    int m0 = blockIdx.x * 64, n0 = blockIdx.y * 64;

    float acc[4][4] = {};

    for (int k0 = 0; k0 < K; k0 += 16) {
        // stage A: 64x16 floats, one float4 per thread
        {
            int row = t >> 2;            // t/4
            int col = (t & 3) * 4;       // (t%4)*4
            int gm = m0 + row;
            float4 av = make_float4(0.f, 0.f, 0.f, 0.f);
            if (gm < M) av = *(const float4*)(A + (size_t)gm * K + k0 + col);
            As[row][col + 0] = av.x; As[row][col + 1] = av.y;
            As[row][col + 2] = av.z; As[row][col + 3] = av.w;
        }
        // stage B: 16x64 floats, one float4 per thread
        {
            int row = t >> 4;            // t/16
            int col = (t & 15) * 4;
            float4 bv = *(const float4*)(B + (size_t)(k0 + row) * N + n0 + col);
            Bs[row][col + 0] = bv.x; Bs[row][col + 1] = bv.y;
            Bs[row][col + 2] = bv.z; Bs[row][col + 3] = bv.w;
        }
        __syncthreads();
#pragma unroll
        for (int k = 0; k < 16; ++k) {
            float a[4], b[4];
#pragma unroll
            for (int i = 0; i < 4; ++i) a[i] = As[ty * 4 + i][k];
#pragma unroll
            for (int j = 0; j < 4; ++j) b[j] = Bs[k][tx * 4 + j];
#pragma unroll
            for (int i = 0; i < 4; ++i)
#pragma unroll
                for (int j = 0; j < 4; ++j) acc[i][j] += a[i] * b[j];
        }
        __syncthreads();
    }

#pragma unroll
    for (int i = 0; i < 4; ++i) {
        int gm = m0 + ty * 4 + i;
        if (gm < M) {
#pragma unroll
            for (int j = 0; j < 4; ++j) {
                int gn = n0 + tx * 4 + j;
                C[(size_t)gm * N + gn] = acc[i][j] + bias[gn];
            }
        }
    }
}

// ---------------- GATv2 aggregation: one wave per node, online softmax ----------------
// lane l covers feature dims l*4..l*4+3 ; head = l>>3 ; head-local dims (l&7)*4..
__global__ __launch_bounds__(256) void gat_agg_kernel(
    const float* __restrict__ fs, const float* __restrict__ fd,
    float* __restrict__ h, const int* __restrict__ offs,
    const int* __restrict__ csr_src, const float* __restrict__ attn_l) {
    int gw = (blockIdx.x * blockDim.x + threadIdx.x) >> 6;
    if (gw >= N_NODES) return;
    int lane = threadIdx.x & 63;
    int node = gw;

    int abase = (lane >> 3) * DH + (lane & 7) * 4;
    float4 av = *(const float4*)(attn_l + abase);
    float a0 = av.x, a1 = av.y, a2 = av.z, a3 = av.w;

    float4 fdv = *(const float4*)(fd + (size_t)node * HID + lane * 4);

    int beg = offs[node], end = offs[node + 1];
    float m = -INFINITY, ssum = 0.f;
    float acc0 = 0.f, acc1 = 0.f, acc2 = 0.f, acc3 = 0.f;

    for (int idx = beg; idx < end; ++idx) {
        int sv = csr_src[idx];
        float4 fsv = *(const float4*)(fs + (size_t)sv * HID + lane * 4);
        float e0 = fsv.x + fdv.x; e0 = e0 > 0.f ? e0 : SLOPE * e0;
        float e1 = fsv.y + fdv.y; e1 = e1 > 0.f ? e1 : SLOPE * e1;
        float e2 = fsv.z + fdv.z; e2 = e2 > 0.f ? e2 : SLOPE * e2;
        float e3 = fsv.w + fdv.w; e3 = e3 > 0.f ? e3 : SLOPE * e3;
        float p = e0 * a0 + e1 * a1 + e2 * a2 + e3 * a3;
        // reduce over the 8 lanes of this head (aligned groups -> xor stays in group)
        p += __shfl_xor(p, 1, 64);
        p += __shfl_xor(p, 2, 64);
        p += __shfl_xor(p, 4, 64);
        float mn = fmaxf(m, p);
        float corr = __expf(m - mn);   // m=-inf first iter -> corr=0
        float w = __expf(p - mn);
        ssum = ssum * corr + w;
        acc0 = acc0 * corr + w * fsv.x;
        acc1 = acc1 * corr + w * fsv.y;
        acc2 = acc2 * corr + w * fsv.z;
        acc3 = acc3 * corr + w * fsv.w;
        m = mn;
    }

    float inv = ssum > 0.f ? 1.f / ssum : 0.f;
    float4 hv = *(const float4*)(h + (size_t)node * HID + lane * 4);
    float4 o;
    o.x = fmaxf(acc0 * inv + hv.x, 0.f);
    o.y = fmaxf(acc1 * inv + hv.y, 0.f);
    o.z = fmaxf(acc2 * inv + hv.z, 0.f);
    o.w = fmaxf(acc3 * inv + hv.w, 0.f);
    *(float4*)(h + (size_t)node * HID + lane * 4) = o;
}

// ---------------- graph sum-pool (graph_ids sorted -> run-length local acc) ----------------
#define POOL_CHUNK 32
__global__ __launch_bounds__(64) void pool_kernel(const float* __restrict__ h,
                                                  const int* __restrict__ gid,
                                                  float* __restrict__ hg) {
    int t = threadIdx.x;
    int n0 = blockIdx.x * POOL_CHUNK;
    int n1 = n0 + POOL_CHUNK; if (n1 > N_NODES) n1 = N_NODES;
    if (n0 >= N_NODES) return;
    float4 acc = make_float4(0.f, 0.f, 0.f, 0.f);
    int cur = gid[n0];
    for (int n = n0; n < n1; ++n) {
        int g = gid[n];
        if (g != cur) {
            atomicAdd(&hg[(size_t)cur * HID + t * 4 + 0], acc.x);
            atomicAdd(&hg[(size_t)cur * HID + t * 4 + 1], acc.y);
            atomicAdd(&hg[(size_t)cur * HID + t * 4 + 2], acc.z);
            atomicAdd(&hg[(size_t)cur * HID + t * 4 + 3], acc.w);
            acc = make_float4(0.f, 0.f, 0.f, 0.f);
            cur = g;
        }
        float4 v = *(const float4*)(h + (size_t)n * HID + t * 4);
        acc.x += v.x; acc.y += v.y; acc.z += v.z; acc.w += v.w;
    }
    atomicAdd(&hg[(size_t)cur * HID + t * 4 + 0], acc.x);
    atomicAdd(&hg[(size_t)cur * HID + t * 4 + 1], acc.y);
    atomicAdd(&hg[(size_t)cur * HID + t * 4 + 2], acc.z);
    atomicAdd(&hg[(size_t)cur * HID + t * 4 + 3], acc.w);
}

// ---------------- classifier: one block per graph ----------------
__global__ __launch_bounds__(256) void classifier_kernel(
    const float* __restrict__ hg,
    const float* __restrict__ Wc1, const float* __restrict__ bc1,
    const float* __restrict__ Wc2, const float* __restrict__ bc2,
    const float* __restrict__ Wc3, const float* __restrict__ bc3,
    float* __restrict__ out) {
    __shared__ float xin[HID];
    __shared__ float x1[HID];
    __shared__ float x2[HID / 2];
    int g = blockIdx.x, t = threadIdx.x;
    xin[t] = hg[(size_t)g * HID + t];
    __syncthreads();
    {
        float acc = bc1[t];
        for (int k = 0; k < HID; ++k) acc += xin[k] * Wc1[k * HID + t];
        x1[t] = fmaxf(acc, 0.f);
    }
    __syncthreads();
    if (t < HID / 2) {
        float acc = bc2[t];
        for (int k = 0; k < HID; ++k) acc += x1[k] * Wc2[k * (HID / 2) + t];
        x2[t] = fmaxf(acc, 0.f);
    }
    __syncthreads();
    if (t < OUT_DIM) {
        float acc = bc3[t];
        for (int k = 0; k < HID / 2; ++k) acc += x2[k] * Wc3[k * OUT_DIM + t];
        out[g * OUT_DIM + t] = acc;
    }
}

// ---------------- launch ----------------
extern "C" void kernel_launch(void* const* d_in, const int* in_sizes, int n_in,
                              void* d_out, int out_size, void* d_ws, size_t ws_size,
                              hipStream_t stream) {
    const float* feature = (const float*)d_in[0];
    const float* W_in   = (const float*)d_in[1];
    const float* b_in   = (const float*)d_in[2];
    const float* W_src  = (const float*)d_in[3];
    const float* b_src  = (const float*)d_in[4];
    const float* W_dst  = (const float*)d_in[5];
    const float* b_dst  = (const float*)d_in[6];
    const float* attn   = (const float*)d_in[7];
    const float* Wc1    = (const float*)d_in[8];
    const float* bc1    = (const float*)d_in[9];
    const float* Wc2    = (const float*)d_in[10];
    const float* bc2    = (const float*)d_in[11];
    const float* Wc3    = (const float*)d_in[12];
    const float* bc3    = (const float*)d_in[13];
    const int* src     = (const int*)d_in[14];
    const int* dst     = (const int*)d_in[15];
    const int* gid     = (const int*)d_in[16];
    float* out = (float*)d_out;

    char* w = (char*)d_ws;
    auto alloc = [&](size_t bytes) -> void* {
        void* p = (void*)w;
        w += (bytes + 255) & ~(size_t)255;
        return p;
    };
    float* h     = (float*)alloc((size_t)N_NODES * HID * 4);
    float* fs    = (float*)alloc((size_t)N_NODES * HID * 4);
    float* fd    = (float*)alloc((size_t)N_NODES * HID * 4);
    float* hg    = (float*)alloc((size_t)NUM_GRAPHS * HID * 4);
    int* cnt     = (int*)alloc((size_t)N_NODES * 4);
    int* offs    = (int*)alloc((size_t)(N_NODES + 1) * 4);
    int* cursor  = (int*)alloc((size_t)N_NODES * 4);
    int* csr_src = (int*)alloc((size_t)N_EDGES * 4);

    // init
    hipLaunchKernelGGL(zero_kernel, dim3((N_NODES + 255) / 256), dim3(256), 0, stream,
                       (float*)cnt, N_NODES);
    hipLaunchKernelGGL(zero_kernel, dim3((NUM_GRAPHS * HID + 255) / 256), dim3(256), 0, stream,
                       hg, NUM_GRAPHS * HID);

    // CSR build by dst
    hipLaunchKernelGGL(count_kernel, dim3((N_EDGES + 255) / 256), dim3(256), 0, stream, dst, cnt);
    hipLaunchKernelGGL(scan_kernel, dim3(1), dim3(256), 0, stream, cnt, offs, cursor);
    hipLaunchKernelGGL(fill_kernel, dim3((N_EDGES + 255) / 256), dim3(256), 0, stream,
                       src, dst, cursor, csr_src);

    // input projection: h = feature @ W_in + b_in
    {
        dim3 grid((N_NODES + 63) / 64, HID / 64);
        hipLaunchKernelGGL(gemm_kernel, grid, dim3(256), 0, stream,
                           feature, W_in, b_in, h, N_NODES, IN_DIM, HID);
    }

    // GATv2 layers
    for (int l = 0; l < LAYERS; ++l) {
        dim3 grid((N_NODES + 63) / 64, HID / 64);
        hipLaunchKernelGGL(gemm_kernel, grid, dim3(256), 0, stream,
                           h, W_src + (size_t)l * HID * HID, b_src + (size_t)l * HID, fs,
                           N_NODES, HID, HID);
        hipLaunchKernelGGL(gemm_kernel, grid, dim3(256), 0, stream,
                           h, W_dst + (size_t)l * HID * HID, b_dst + (size_t)l * HID, fd,
                           N_NODES, HID, HID);
        hipLaunchKernelGGL(gat_agg_kernel, dim3((N_NODES * 64 + 255) / 256), dim3(256), 0, stream,
                           fs, fd, h, offs, csr_src, attn + (size_t)l * HEADS * DH);
    }

    // pool + classifier
    hipLaunchKernelGGL(pool_kernel, dim3((N_NODES + POOL_CHUNK - 1) / POOL_CHUNK), dim3(64), 0, stream,
                       h, gid, hg);
    hipLaunchKernelGGL(classifier_kernel, dim3(NUM_GRAPHS), dim3(256), 0, stream,
                       hg, Wc1, bc1, Wc2, bc2, Wc3, bc3, out);
}